// Round 9
// baseline (863.241 us; speedup 1.0000x reference)
//
#include <hip/hip_runtime.h>
#include <hip/hip_bf16.h>

typedef __attribute__((ext_vector_type(8))) __bf16 bx8;
typedef __attribute__((ext_vector_type(4))) float  fx4;

#define ROWS 8192   // B*S
#define HID  1024
#define MEMN 8192

// global_load_lds, 16B per lane; LDS dest = wave-uniform base + lane*16
#define GLDS(gp, lp) __builtin_amdgcn_global_load_lds( \
    (const __attribute__((address_space(1))) void*)(gp), \
    (__attribute__((address_space(3))) void*)(lp), 16, 0, 0)

#define MEMFENCE asm volatile("" ::: "memory")

// ---------------------------------------------------------------------------
// fp32 -> bf16 elementwise convert
// ---------------------------------------------------------------------------
__global__ __launch_bounds__(256)
void f32_to_bf16_vec(const float* __restrict__ in, __bf16* __restrict__ out)
{
    const size_t i = ((size_t)blockIdx.x * 256 + threadIdx.x) * 8;
    fx4 a = *(const fx4*)(in + i);
    fx4 b = *(const fx4*)(in + i + 4);
    bx8 u;
    u[0] = (__bf16)a[0]; u[1] = (__bf16)a[1]; u[2] = (__bf16)a[2]; u[3] = (__bf16)a[3];
    u[4] = (__bf16)b[0]; u[5] = (__bf16)b[1]; u[6] = (__bf16)b[2]; u[7] = (__bf16)b[3];
    *(bx8*)(out + i) = u;
}

// ---------------------------------------------------------------------------
// fp32 [R][C] -> bf16 [C][R] transpose (64x64 tiles via LDS)
// ---------------------------------------------------------------------------
__global__ __launch_bounds__(256)
void transpose_f32_to_bf16(const float* __restrict__ in, __bf16* __restrict__ out,
                           int R, int C)
{
    __shared__ float t[64][65];
    const int tid = threadIdx.x;
    const int r0 = blockIdx.y * 64;
    const int c0 = blockIdx.x * 64;
    const int lr = tid >> 4;
    const int lc = (tid & 15) * 4;
#pragma unroll
    for (int p = 0; p < 4; ++p) {
        const int rr = p * 16 + lr;
        const fx4 v = *(const fx4*)(in + (size_t)(r0 + rr) * C + c0 + lc);
        t[rr][lc + 0] = v[0]; t[rr][lc + 1] = v[1];
        t[rr][lc + 2] = v[2]; t[rr][lc + 3] = v[3];
    }
    __syncthreads();
    const int oc = tid >> 2;
    const int ob = (tid & 3) * 16;
    bx8 u0, u1;
#pragma unroll
    for (int j = 0; j < 8; ++j) {
        u0[j] = (__bf16)t[ob + j][oc];
        u1[j] = (__bf16)t[ob + 8 + j][oc];
    }
    *(bx8*)(out + (size_t)(c0 + oc) * R + r0 + ob)     = u0;
    *(bx8*)(out + (size_t)(c0 + oc) * R + r0 + ob + 8) = u1;
}

// ---------------------------------------------------------------------------
// Row softmax over 8192 bf16 logits, in place (read path). fp32 math.
// ---------------------------------------------------------------------------
__global__ __launch_bounds__(256)
void softmax_rows(__bf16* __restrict__ W)
{
    __bf16* row = W + (size_t)blockIdx.x * MEMN;
    const int tid = threadIdx.x;
    float v[32];
#pragma unroll
    for (int i = 0; i < 4; ++i) {
        bx8 u = *(const bx8*)(row + i * 2048 + tid * 8);
#pragma unroll
        for (int j = 0; j < 8; ++j) v[i * 8 + j] = (float)u[j];
    }
    float m = -1e30f;
#pragma unroll
    for (int i = 0; i < 32; ++i) m = fmaxf(m, v[i]);
#pragma unroll
    for (int off = 32; off >= 1; off >>= 1) m = fmaxf(m, __shfl_xor(m, off, 64));
    __shared__ float red[8];
    const int wave = tid >> 6, lane = tid & 63;
    if (lane == 0) red[wave] = m;
    __syncthreads();
    m = fmaxf(fmaxf(red[0], red[1]), fmaxf(red[2], red[3]));
    float s = 0.f;
#pragma unroll
    for (int i = 0; i < 32; ++i) { v[i] = __expf(v[i] - m); s += v[i]; }
#pragma unroll
    for (int off = 32; off >= 1; off >>= 1) s += __shfl_xor(s, off, 64);
    if (lane == 0) red[4 + wave] = s;
    __syncthreads();
    s = (red[4] + red[5]) + (red[6] + red[7]);
    const float inv = 1.0f / s;
#pragma unroll
    for (int i = 0; i < 4; ++i) {
        bx8 u;
#pragma unroll
        for (int j = 0; j < 8; ++j) u[j] = (__bf16)(v[i * 8 + j] * inv);
        *(bx8*)(row + i * 2048 + tid * 8) = u;
    }
}

// ---------------------------------------------------------------------------
// Row softmax STATS only (write path): per-row (max, 1/sum) -> stats[row].
// ---------------------------------------------------------------------------
__global__ __launch_bounds__(256)
void softmax_stats(const __bf16* __restrict__ W, float2* __restrict__ stats)
{
    const __bf16* row = W + (size_t)blockIdx.x * MEMN;
    const int tid = threadIdx.x;
    float v[32];
#pragma unroll
    for (int i = 0; i < 4; ++i) {
        bx8 u = *(const bx8*)(row + i * 2048 + tid * 8);
#pragma unroll
        for (int j = 0; j < 8; ++j) v[i * 8 + j] = (float)u[j];
    }
    float m = -1e30f;
#pragma unroll
    for (int i = 0; i < 32; ++i) m = fmaxf(m, v[i]);
#pragma unroll
    for (int off = 32; off >= 1; off >>= 1) m = fmaxf(m, __shfl_xor(m, off, 64));
    __shared__ float red[8];
    const int wave = tid >> 6, lane = tid & 63;
    if (lane == 0) red[wave] = m;
    __syncthreads();
    m = fmaxf(fmaxf(red[0], red[1]), fmaxf(red[2], red[3]));
    float s = 0.f;
#pragma unroll
    for (int i = 0; i < 32; ++i) s += __expf(v[i] - m);
#pragma unroll
    for (int off = 32; off >= 1; off >>= 1) s += __shfl_xor(s, off, 64);
    if (lane == 0) red[4 + wave] = s;
    __syncthreads();
    if (tid == 0) {
        s = (red[4] + red[5]) + (red[6] + red[7]);
        stats[blockIdx.x] = make_float2(m, 1.0f / s);
    }
}

// ---------------------------------------------------------------------------
// In-place scale+transpose of W: W <- softmax(W)^T using per-source-row stats.
// ---------------------------------------------------------------------------
__global__ __launch_bounds__(256)
void scale_transpose_inplace(__bf16* __restrict__ W,
                             const float2* __restrict__ stats)
{
    const int bi = blockIdx.y;
    const int bj = blockIdx.x;
    if (bi > bj) return;
    __shared__ __bf16 ta[64][72];
    __shared__ __bf16 tb[64][72];
    const int tid = threadIdx.x;
    const int lr = tid >> 3;
    const int lc = (tid & 7) * 8;
    const size_t N = MEMN;
    __bf16* At = W + (size_t)bi * 64 * N + (size_t)bj * 64;
    __bf16* Bt = W + (size_t)bj * 64 * N + (size_t)bi * 64;
#pragma unroll
    for (int p = 0; p < 2; ++p) {
        const int rr = p * 32 + lr;
        const float2 sa = stats[bi * 64 + rr];
        const float2 sb = stats[bj * 64 + rr];
        bx8 va = *(const bx8*)(At + (size_t)rr * N + lc);
        bx8 vb = *(const bx8*)(Bt + (size_t)rr * N + lc);
#pragma unroll
        for (int j = 0; j < 8; ++j) {
            ta[rr][lc + j] = (__bf16)(__expf((float)va[j] - sa.x) * sa.y);
            tb[rr][lc + j] = (__bf16)(__expf((float)vb[j] - sb.x) * sb.y);
        }
    }
    __syncthreads();
    const int oc = tid >> 2;
    const int ob = (tid & 3) * 16;
    bx8 u0, u1, v0, v1;
#pragma unroll
    for (int j = 0; j < 8; ++j) {
        u0[j] = tb[ob + j][oc];  u1[j] = tb[ob + 8 + j][oc];
        v0[j] = ta[ob + j][oc];  v1[j] = ta[ob + 8 + j][oc];
    }
    *(bx8*)(At + (size_t)oc * N + ob)     = u0;
    *(bx8*)(At + (size_t)oc * N + ob + 8) = u1;
    *(bx8*)(Bt + (size_t)oc * N + ob)     = v0;
    *(bx8*)(Bt + (size_t)oc * N + ob + 8) = v1;
}

// ---------------------------------------------------------------------------
// gemm8f: round-3 ring-4 NT GEMM + FRAGMENT DOUBLE-BUFFERING.
// K-loop unrolled x2 with named register sets F0/F1 (static indexing, rule 20).
// Per half-iteration: {stage(t+2) -> vmcnt(L) -> barrier -> ds_read F(next)
// -> MFMA F(cur)}. The ds_reads for tile t+1 issue into the ALTERNATE register
// set while tile t's MFMA cluster drains -> no WAR serialization between the
// DS window and the MFMA window; consecutive MFMA clusters use the already-
// loaded set, so the matrix pipe stays fed across barriers.
// Race ledger identical to round 3 (PMC-verified): ring-4 slots; ds_read of
// slot (t+1)&3 occurs after a barrier at which every wave's vmcnt(L) forced
// stage(t+1) to have landed; stage(t+2) overwrites a slot whose readers
// retired >=2 barriers earlier.
// MODE 0: bf16 out + bias[col]; MODE 1: f32 out; MODE 2: f32 out + add[idx].
// ---------------------------------------------------------------------------
template <int BM, int BN, int MODE>
__global__ __launch_bounds__(512)
void gemm8f(const __bf16* __restrict__ A, const __bf16* __restrict__ B,
            const float* __restrict__ bias, const float* __restrict__ add,
            void* __restrict__ out, int N, int K, int nBN)
{
    constexpr int ASZ = BM * 64;
    constexpr int BSZ = BN * 64;
    constexpr int RA  = BM / 128;
    constexpr int RB  = BN / 128;
    constexpr int L   = RA + RB;
    constexpr int RWM = BM / 2, RWN = BN / 4;
    constexpr int FM  = RWM / 16, FN = RWN / 16;

    __shared__ __align__(16) char smem[4 * (ASZ + BSZ)];

    const int tid = threadIdx.x;
    const int wid = tid >> 6;
    const int ln  = tid & 63;
    const int fl  = ln & 15;
    const int fh  = ln >> 4;
    const int wr  = wid >> 2;
    const int wc  = wid & 3;

    const int nwg = gridDim.x;
    const int bid = blockIdx.x;
    const int wg  = (bid & 7) * (nwg >> 3) + (bid >> 3);
    const int tm  = (wg / nBN) * BM;
    const int tn  = (wg % nBN) * BN;

    const int NT = K / 32;      // always even here (K = 1024 or 8192)

    const __bf16* Ag[RA];
    const __bf16* Bg[RB];
#pragma unroll
    for (int R = 0; R < RA; ++R) {
        const int p = R * 512 + tid;
        Ag[R] = A + (size_t)(tm + (p >> 2)) * K + ((p & 3) ^ ((p >> 3) & 3)) * 8;
    }
#pragma unroll
    for (int R = 0; R < RB; ++R) {
        const int p = R * 512 + tid;
        Bg[R] = B + (size_t)(tn + (p >> 2)) * K + ((p & 3) ^ ((p >> 3) & 3)) * 8;
    }

    auto stage = [&](int t) {
        const int s = t & 3;
        const size_t ko = (size_t)t * 32;
        char* Ad = smem + s * ASZ + wid * 1024;
        char* Bd = smem + 4 * ASZ + s * BSZ + wid * 1024;
#pragma unroll
        for (int R = 0; R < RA; ++R) GLDS(Ag[R] + ko, Ad + R * 8192);
#pragma unroll
        for (int R = 0; R < RB; ++R) GLDS(Bg[R] + ko, Bd + R * 8192);
    };

    bx8 Fa0[FM], Fb0[FN], Fa1[FM], Fb1[FN];

    auto dsread = [&](int slot, bx8 (&fa)[FM], bx8 (&fb)[FN]) {
        const char* Ab = smem + slot * ASZ;
        const char* Bb = smem + 4 * ASZ + slot * BSZ;
#pragma unroll
        for (int mi = 0; mi < FM; ++mi) {
            const int r = wr * RWM + mi * 16 + fl;
            fa[mi] = *(const bx8*)(Ab + r * 64 + ((fh ^ ((r >> 1) & 3)) << 4));
        }
#pragma unroll
        for (int ni = 0; ni < FN; ++ni) {
            const int c = wc * RWN + ni * 16 + fl;
            fb[ni] = *(const bx8*)(Bb + c * 64 + ((fh ^ ((c >> 1) & 3)) << 4));
        }
    };

    fx4 acc[FM][FN] = {};

    auto mfma = [&](bx8 (&fa)[FM], bx8 (&fb)[FN]) {
        __builtin_amdgcn_s_setprio(1);
#pragma unroll
        for (int mi = 0; mi < FM; ++mi)
#pragma unroll
            for (int ni = 0; ni < FN; ++ni)
                acc[mi][ni] = __builtin_amdgcn_mfma_f32_16x16x32_bf16(
                    fa[mi], fb[ni], acc[mi][ni], 0, 0, 0);
        __builtin_amdgcn_s_setprio(0);
    };

    // prologue: stage 0,1; wait stage(0); read tile-0 fragments into F0
    stage(0);
    stage(1);
    asm volatile("s_waitcnt vmcnt(%0)" :: "i"(L) : "memory");
    __builtin_amdgcn_s_barrier();
    MEMFENCE;
    dsread(0, Fa0, Fb0);

    for (int tt = 0; tt < NT; tt += 2) {
        // ---- half 1: compute tile tt (F0), prefetch fragments of tt+1 -> F1
        if (tt + 2 < NT) {
            stage(tt + 2);
            asm volatile("s_waitcnt vmcnt(%0)" :: "i"(L) : "memory");
        } else {
            asm volatile("s_waitcnt vmcnt(0)" ::: "memory");
        }
        __builtin_amdgcn_s_barrier();
        MEMFENCE;
        dsread((tt + 1) & 3, Fa1, Fb1);
        mfma(Fa0, Fb0);

        // ---- half 2: compute tile tt+1 (F1), prefetch fragments of tt+2 -> F0
        if (tt + 3 < NT) {
            stage(tt + 3);
            asm volatile("s_waitcnt vmcnt(%0)" :: "i"(L) : "memory");
        } else {
            asm volatile("s_waitcnt vmcnt(0)" ::: "memory");
        }
        __builtin_amdgcn_s_barrier();
        MEMFENCE;
        if (tt + 2 < NT) dsread((tt + 2) & 3, Fa0, Fb0);
        mfma(Fa1, Fb1);
    }

    // epilogue: C/D layout col = lane&15, row = (lane>>4)*4 + reg
#pragma unroll
    for (int mi = 0; mi < FM; ++mi) {
#pragma unroll
        for (int ni = 0; ni < FN; ++ni) {
            const int gr0 = tm + wr * RWM + mi * 16 + fh * 4;
            const int gc  = tn + wc * RWN + ni * 16 + fl;
            fx4 c = acc[mi][ni];
            if constexpr (MODE == 0) {
                __bf16* O = (__bf16*)out;
                const float bv = bias[gc];
#pragma unroll
                for (int j = 0; j < 4; ++j)
                    O[(size_t)(gr0 + j) * N + gc] = (__bf16)(c[j] + bv);
            } else if constexpr (MODE == 1) {
                float* O = (float*)out;
#pragma unroll
                for (int j = 0; j < 4; ++j)
                    O[(size_t)(gr0 + j) * N + gc] = c[j];
            } else {
                float* O = (float*)out;
#pragma unroll
                for (int j = 0; j < 4; ++j) {
                    const size_t idx = (size_t)(gr0 + j) * N + gc;
                    O[idx] = c[j] + add[idx];
                }
            }
        }
    }
}

// ---------------------------------------------------------------------------
// Orchestration. ws layout (176 MiB):
//   xb    [8192,1024] bf16  @ 0
//   slot1 [8192,1024] bf16  @ 16 MiB  (rwb, then wwb, then stats)
//   slot2 [1024,8192] bf16  @ 32 MiB  (memT then xT)
//   W     [8192,8192] bf16  @ 48 MiB
// ---------------------------------------------------------------------------
extern "C" void kernel_launch(void* const* d_in, const int* in_sizes, int n_in,
                              void* d_out, int out_size, void* d_ws, size_t ws_size,
                              hipStream_t stream)
{
    const float* x       = (const float*)d_in[0];
    const float* memory  = (const float*)d_in[1];
    const float* read_w  = (const float*)d_in[2];
    const float* read_b  = (const float*)d_in[3];
    const float* write_w = (const float*)d_in[4];
    const float* write_b = (const float*)d_in[5];

    float* out_read = (float*)d_out;
    float* out_mem  = (float*)d_out + (size_t)MEMN * HID;

    char* p = (char*)d_ws;
    const size_t MiB = 1024 * 1024;
    __bf16* xb    = (__bf16*)(p + 0 * MiB);
    __bf16* slot1 = (__bf16*)(p + 16 * MiB);
    __bf16* slot2 = (__bf16*)(p + 32 * MiB);
    __bf16* W     = (__bf16*)(p + 48 * MiB);
    float2* stats = (float2*)(p + 16 * MiB);

    // ---- read path ---------------------------------------------------------
    f32_to_bf16_vec<<<4096, 256, 0, stream>>>(x, xb);
    f32_to_bf16_vec<<<4096, 256, 0, stream>>>(read_w, slot1);
    transpose_f32_to_bf16<<<dim3(HID / 64, ROWS / 64), 256, 0, stream>>>(memory, slot2, ROWS, HID);
    gemm8f<128, 256, 0><<<(ROWS / 128) * (MEMN / 256), 512, 0, stream>>>(
        xb, slot1, read_b, nullptr, W, MEMN, HID, MEMN / 256);
    softmax_rows<<<ROWS, 256, 0, stream>>>(W);
    gemm8f<128, 256, 1><<<(ROWS / 128) * (HID / 256), 512, 0, stream>>>(
        W, slot2, nullptr, nullptr, out_read, HID, MEMN, HID / 256);

    // ---- write path --------------------------------------------------------
    f32_to_bf16_vec<<<4096, 256, 0, stream>>>(write_w, slot1);
    transpose_f32_to_bf16<<<dim3(HID / 64, ROWS / 64), 256, 0, stream>>>(x, slot2, ROWS, HID);
    gemm8f<128, 256, 0><<<(ROWS / 128) * (MEMN / 256), 512, 0, stream>>>(
        xb, slot1, write_b, nullptr, W, MEMN, HID, MEMN / 256);
    softmax_stats<<<ROWS, 256, 0, stream>>>(W, stats);
    scale_transpose_inplace<<<dim3(MEMN / 64, MEMN / 64), 256, 0, stream>>>(W, stats);
    gemm8f<128, 256, 2><<<(MEMN / 128) * (HID / 256), 512, 0, stream>>>(
        W, slot2, nullptr, memory, out_mem, HID, ROWS, HID / 256);
}

// Round 10
// 809.280 us; speedup vs baseline: 1.0667x; 1.0667x over previous
//
#include <hip/hip_runtime.h>
#include <hip/hip_bf16.h>

typedef __attribute__((ext_vector_type(8)))  __bf16 bx8;
typedef __attribute__((ext_vector_type(4)))  float  fx4;
typedef __attribute__((ext_vector_type(16))) float  fx16;

#define ROWS 8192   // B*S
#define HID  1024
#define MEMN 8192

// global_load_lds, 16B per lane; LDS dest = wave-uniform base + lane*16
#define GLDS(gp, lp) __builtin_amdgcn_global_load_lds( \
    (const __attribute__((address_space(1))) void*)(gp), \
    (__attribute__((address_space(3))) void*)(lp), 16, 0, 0)

#define MEMFENCE asm volatile("" ::: "memory")

// ---------------------------------------------------------------------------
// fp32 -> bf16 elementwise convert
// ---------------------------------------------------------------------------
__global__ __launch_bounds__(256)
void f32_to_bf16_vec(const float* __restrict__ in, __bf16* __restrict__ out)
{
    const size_t i = ((size_t)blockIdx.x * 256 + threadIdx.x) * 8;
    fx4 a = *(const fx4*)(in + i);
    fx4 b = *(const fx4*)(in + i + 4);
    bx8 u;
    u[0] = (__bf16)a[0]; u[1] = (__bf16)a[1]; u[2] = (__bf16)a[2]; u[3] = (__bf16)a[3];
    u[4] = (__bf16)b[0]; u[5] = (__bf16)b[1]; u[6] = (__bf16)b[2]; u[7] = (__bf16)b[3];
    *(bx8*)(out + i) = u;
}

// ---------------------------------------------------------------------------
// fp32 [R][C] -> bf16 [C][R] transpose (64x64 tiles via LDS)
// ---------------------------------------------------------------------------
__global__ __launch_bounds__(256)
void transpose_f32_to_bf16(const float* __restrict__ in, __bf16* __restrict__ out,
                           int R, int C)
{
    __shared__ float t[64][65];
    const int tid = threadIdx.x;
    const int r0 = blockIdx.y * 64;
    const int c0 = blockIdx.x * 64;
    const int lr = tid >> 4;
    const int lc = (tid & 15) * 4;
#pragma unroll
    for (int p = 0; p < 4; ++p) {
        const int rr = p * 16 + lr;
        const fx4 v = *(const fx4*)(in + (size_t)(r0 + rr) * C + c0 + lc);
        t[rr][lc + 0] = v[0]; t[rr][lc + 1] = v[1];
        t[rr][lc + 2] = v[2]; t[rr][lc + 3] = v[3];
    }
    __syncthreads();
    const int oc = tid >> 2;
    const int ob = (tid & 3) * 16;
    bx8 u0, u1;
#pragma unroll
    for (int j = 0; j < 8; ++j) {
        u0[j] = (__bf16)t[ob + j][oc];
        u1[j] = (__bf16)t[ob + 8 + j][oc];
    }
    *(bx8*)(out + (size_t)(c0 + oc) * R + r0 + ob)     = u0;
    *(bx8*)(out + (size_t)(c0 + oc) * R + r0 + ob + 8) = u1;
}

// ---------------------------------------------------------------------------
// In-place transpose of square bf16 matrix W [MEMN][MEMN], 64x64 tile pairs.
// ---------------------------------------------------------------------------
__global__ __launch_bounds__(256)
void transpose_inplace_bf16(__bf16* __restrict__ W)
{
    const int bi = blockIdx.y;
    const int bj = blockIdx.x;
    if (bi > bj) return;
    __shared__ __bf16 ta[64][72];
    __shared__ __bf16 tb[64][72];
    const int tid = threadIdx.x;
    const int lr = tid >> 3;
    const int lc = (tid & 7) * 8;
    const size_t N = MEMN;
    __bf16* At = W + (size_t)bi * 64 * N + (size_t)bj * 64;
    __bf16* Bt = W + (size_t)bj * 64 * N + (size_t)bi * 64;
#pragma unroll
    for (int p = 0; p < 2; ++p) {
        const int rr = p * 32 + lr;
        *(bx8*)(&ta[rr][lc]) = *(const bx8*)(At + (size_t)rr * N + lc);
        *(bx8*)(&tb[rr][lc]) = *(const bx8*)(Bt + (size_t)rr * N + lc);
    }
    __syncthreads();
    const int oc = tid >> 2;
    const int ob = (tid & 3) * 16;
    bx8 u0, u1, v0, v1;
#pragma unroll
    for (int j = 0; j < 8; ++j) {
        u0[j] = tb[ob + j][oc];  u1[j] = tb[ob + 8 + j][oc];
        v0[j] = ta[ob + j][oc];  v1[j] = ta[ob + 8 + j][oc];
    }
    *(bx8*)(At + (size_t)oc * N + ob)     = u0;
    *(bx8*)(At + (size_t)oc * N + ob + 8) = u1;
    *(bx8*)(Bt + (size_t)oc * N + ob)     = v0;
    *(bx8*)(Bt + (size_t)oc * N + ob + 8) = v1;
}

// ---------------------------------------------------------------------------
// Row softmax over 8192 bf16 logits, in place. One block/row, fp32 math.
// ---------------------------------------------------------------------------
__global__ __launch_bounds__(256)
void softmax_rows(__bf16* __restrict__ W)
{
    __bf16* row = W + (size_t)blockIdx.x * MEMN;
    const int tid = threadIdx.x;
    float v[32];
#pragma unroll
    for (int i = 0; i < 4; ++i) {
        bx8 u = *(const bx8*)(row + i * 2048 + tid * 8);
#pragma unroll
        for (int j = 0; j < 8; ++j) v[i * 8 + j] = (float)u[j];
    }
    float m = -1e30f;
#pragma unroll
    for (int i = 0; i < 32; ++i) m = fmaxf(m, v[i]);
#pragma unroll
    for (int off = 32; off >= 1; off >>= 1) m = fmaxf(m, __shfl_xor(m, off, 64));
    __shared__ float red[8];
    const int wave = tid >> 6, lane = tid & 63;
    if (lane == 0) red[wave] = m;
    __syncthreads();
    m = fmaxf(fmaxf(red[0], red[1]), fmaxf(red[2], red[3]));
    float s = 0.f;
#pragma unroll
    for (int i = 0; i < 32; ++i) { v[i] = __expf(v[i] - m); s += v[i]; }
#pragma unroll
    for (int off = 32; off >= 1; off >>= 1) s += __shfl_xor(s, off, 64);
    if (lane == 0) red[4 + wave] = s;
    __syncthreads();
    s = (red[4] + red[5]) + (red[6] + red[7]);
    const float inv = 1.0f / s;
#pragma unroll
    for (int i = 0; i < 4; ++i) {
        bx8 u;
#pragma unroll
        for (int j = 0; j < 8; ++j) u[j] = (__bf16)(v[i * 8 + j] * inv);
        *(bx8*)(row + i * 2048 + tid * 8) = u;
    }
}

// ---------------------------------------------------------------------------
// gemm32: round-3 ring-4 NT GEMM structure, 32x32x16 MFMA.
// C[i,j] = sum_k A[i,k]*B[j,k]. BMxBN tile, BK=32, 512 thr = 8 waves (2Mx4N),
// wave tile (BM/2)x(BN/4) as FMxFN fragments of 32x32, FM=BM/64, FN=BN/128.
// Ring-4 LDS slots; one counted s_waitcnt vmcnt(L) + one s_barrier per K-tile
// (round-3 ledger, PMC-verified race-free); stage(t+2) after the barrier.
// Swizzle identical to round 3 (0 bank conflicts PMC-verified; 32x32 read
// pattern re-derived conflict-free: per bank 8 touches = minimum).
// Fragment layouts: A/B row=lane&31, k=(lane>>5)*8+j (gfx950 2xK family);
// C/D col=lane&31, row=(reg&3)+8*(reg>>2)+4*(lane>>5)  [m74/m101-verified].
// MODE 0: bf16 out + bias[col]; MODE 1: f32 out; MODE 2: f32 out + add[idx].
// ---------------------------------------------------------------------------
template <int BM, int BN, int MODE>
__global__ __launch_bounds__(512)
void gemm32(const __bf16* __restrict__ A, const __bf16* __restrict__ B,
            const float* __restrict__ bias, const float* __restrict__ add,
            void* __restrict__ out, int N, int K, int nBN)
{
    constexpr int ASZ = BM * 64;
    constexpr int BSZ = BN * 64;
    constexpr int RA  = BM / 128;
    constexpr int RB  = BN / 128;
    constexpr int L   = RA + RB;
    constexpr int RWM = BM / 2, RWN = BN / 4;
    constexpr int FM  = RWM / 32, FN = RWN / 32;

    __shared__ __align__(16) char smem[4 * (ASZ + BSZ)];

    const int tid = threadIdx.x;
    const int wid = tid >> 6;
    const int ln  = tid & 63;
    const int l31 = ln & 31;           // row/col within a 32-fragment
    const int lk  = ln >> 5;           // k-subgroup (0..1)
    const int wr  = wid >> 2;
    const int wc  = wid & 3;

    const int nwg = gridDim.x;
    const int bid = blockIdx.x;
    const int wg  = (bid & 7) * (nwg >> 3) + (bid >> 3);
    const int tm  = (wg / nBN) * BM;
    const int tn  = (wg % nBN) * BN;

    const int NT = K / 32;

    const __bf16* Ag[RA];
    const __bf16* Bg[RB];
#pragma unroll
    for (int R = 0; R < RA; ++R) {
        const int p = R * 512 + tid;
        Ag[R] = A + (size_t)(tm + (p >> 2)) * K + ((p & 3) ^ ((p >> 3) & 3)) * 8;
    }
#pragma unroll
    for (int R = 0; R < RB; ++R) {
        const int p = R * 512 + tid;
        Bg[R] = B + (size_t)(tn + (p >> 2)) * K + ((p & 3) ^ ((p >> 3) & 3)) * 8;
    }

    auto stage = [&](int t) {
        const int s = t & 3;
        const size_t ko = (size_t)t * 32;
        char* Ad = smem + s * ASZ + wid * 1024;
        char* Bd = smem + 4 * ASZ + s * BSZ + wid * 1024;
#pragma unroll
        for (int R = 0; R < RA; ++R) GLDS(Ag[R] + ko, Ad + R * 8192);
#pragma unroll
        for (int R = 0; R < RB; ++R) GLDS(Bg[R] + ko, Bd + R * 8192);
    };

    fx16 acc[FM][FN] = {};

    stage(0);
    if (NT > 1) stage(1);

    for (int t = 0; t < NT; ++t) {
        if (t == NT - 1) {
            asm volatile("s_waitcnt vmcnt(0)" ::: "memory");
        } else {
            asm volatile("s_waitcnt vmcnt(%0)" :: "i"(L) : "memory");
        }
        __builtin_amdgcn_s_barrier();
        MEMFENCE;
        if (t + 2 < NT) stage(t + 2);

        const char* Ab = smem + (t & 3) * ASZ;
        const char* Bb = smem + 4 * ASZ + (t & 3) * BSZ;

        bx8 fa[2][FM], fb[2][FN];
#pragma unroll
        for (int kk = 0; kk < 2; ++kk) {
#pragma unroll
            for (int mi = 0; mi < FM; ++mi) {
                const int r = wr * RWM + mi * 32 + l31;
                const int g = (kk * 2 + lk) ^ ((r >> 1) & 3);
                fa[kk][mi] = *(const bx8*)(Ab + r * 64 + (g << 4));
            }
#pragma unroll
            for (int ni = 0; ni < FN; ++ni) {
                const int c = wc * RWN + ni * 32 + l31;
                const int g = (kk * 2 + lk) ^ ((c >> 1) & 3);
                fb[kk][ni] = *(const bx8*)(Bb + c * 64 + (g << 4));
            }
        }
        __builtin_amdgcn_s_setprio(1);
#pragma unroll
        for (int mi = 0; mi < FM; ++mi)
#pragma unroll
            for (int ni = 0; ni < FN; ++ni)
#pragma unroll
                for (int kk = 0; kk < 2; ++kk)
                    acc[mi][ni] = __builtin_amdgcn_mfma_f32_32x32x16_bf16(
                        fa[kk][mi], fb[kk][ni], acc[mi][ni], 0, 0, 0);
        __builtin_amdgcn_s_setprio(0);
    }

    // epilogue: C/D col = lane&31, row = (reg&3) + 8*(reg>>2) + 4*(lane>>5)
#pragma unroll
    for (int mi = 0; mi < FM; ++mi) {
#pragma unroll
        for (int ni = 0; ni < FN; ++ni) {
            const int gc    = tn + wc * RWN + ni * 32 + l31;
            const int rbase = tm + wr * RWM + mi * 32 + 4 * lk;
            fx16 c = acc[mi][ni];
            if constexpr (MODE == 0) {
                __bf16* O = (__bf16*)out;
                const float bv = bias[gc];
#pragma unroll
                for (int rg = 0; rg < 4; ++rg)
#pragma unroll
                    for (int j = 0; j < 4; ++j)
                        O[(size_t)(rbase + rg * 8 + j) * N + gc] =
                            (__bf16)(c[rg * 4 + j] + bv);
            } else if constexpr (MODE == 1) {
                float* O = (float*)out;
#pragma unroll
                for (int rg = 0; rg < 4; ++rg)
#pragma unroll
                    for (int j = 0; j < 4; ++j)
                        O[(size_t)(rbase + rg * 8 + j) * N + gc] = c[rg * 4 + j];
            } else {
                float* O = (float*)out;
#pragma unroll
                for (int rg = 0; rg < 4; ++rg)
#pragma unroll
                    for (int j = 0; j < 4; ++j) {
                        const size_t idx = (size_t)(rbase + rg * 8 + j) * N + gc;
                        O[idx] = c[rg * 4 + j] + add[idx];
                    }
            }
        }
    }
}

// ---------------------------------------------------------------------------
// Orchestration. ws layout (176 MiB):
//   xb    [8192,1024] bf16  @ 0
//   slot1 [8192,1024] bf16  @ 16 MiB  (rwb then wwb)
//   slot2 [1024,8192] bf16  @ 32 MiB  (memT then xT)
//   W     [8192,8192] bf16  @ 48 MiB
// ---------------------------------------------------------------------------
extern "C" void kernel_launch(void* const* d_in, const int* in_sizes, int n_in,
                              void* d_out, int out_size, void* d_ws, size_t ws_size,
                              hipStream_t stream)
{
    const float* x       = (const float*)d_in[0];
    const float* memory  = (const float*)d_in[1];
    const float* read_w  = (const float*)d_in[2];
    const float* read_b  = (const float*)d_in[3];
    const float* write_w = (const float*)d_in[4];
    const float* write_b = (const float*)d_in[5];

    float* out_read = (float*)d_out;
    float* out_mem  = (float*)d_out + (size_t)MEMN * HID;

    char* p = (char*)d_ws;
    const size_t MiB = 1024 * 1024;
    __bf16* xb    = (__bf16*)(p + 0 * MiB);
    __bf16* slot1 = (__bf16*)(p + 16 * MiB);
    __bf16* slot2 = (__bf16*)(p + 32 * MiB);
    __bf16* W     = (__bf16*)(p + 48 * MiB);

    // ---- read path ---------------------------------------------------------
    f32_to_bf16_vec<<<4096, 256, 0, stream>>>(x, xb);
    f32_to_bf16_vec<<<4096, 256, 0, stream>>>(read_w, slot1);
    transpose_f32_to_bf16<<<dim3(HID / 64, ROWS / 64), 256, 0, stream>>>(memory, slot2, ROWS, HID);
    gemm32<256, 256, 0><<<(ROWS / 256) * (MEMN / 256), 512, 0, stream>>>(
        xb, slot1, read_b, nullptr, W, MEMN, HID, MEMN / 256);
    softmax_rows<<<ROWS, 256, 0, stream>>>(W);
    gemm32<128, 256, 1><<<(ROWS / 128) * (HID / 256), 512, 0, stream>>>(
        W, slot2, nullptr, nullptr, out_read, HID, MEMN, HID / 256);

    // ---- write path --------------------------------------------------------
    f32_to_bf16_vec<<<4096, 256, 0, stream>>>(write_w, slot1);
    transpose_f32_to_bf16<<<dim3(HID / 64, ROWS / 64), 256, 0, stream>>>(x, slot2, ROWS, HID);
    gemm32<256, 256, 0><<<(ROWS / 256) * (MEMN / 256), 512, 0, stream>>>(
        xb, slot1, write_b, nullptr, W, MEMN, HID, MEMN / 256);
    softmax_rows<<<ROWS, 256, 0, stream>>>(W);
    transpose_inplace_bf16<<<dim3(MEMN / 64, MEMN / 64), 256, 0, stream>>>(W);
    gemm32<128, 256, 2><<<(MEMN / 128) * (HID / 256), 512, 0, stream>>>(
        W, slot2, nullptr, memory, out_mem, HID, ROWS, HID / 256);
}

// Round 11
// 670.453 us; speedup vs baseline: 1.2875x; 1.2071x over previous
//
#include <hip/hip_runtime.h>
#include <hip/hip_bf16.h>

typedef __attribute__((ext_vector_type(8))) __bf16 bx8;
typedef __attribute__((ext_vector_type(4))) float  fx4;

#define ROWS 8192   // B*S
#define HID  1024
#define MEMN 8192

// global_load_lds, 16B per lane; LDS dest = wave-uniform base + lane*16
#define GLDS(gp, lp) __builtin_amdgcn_global_load_lds( \
    (const __attribute__((address_space(1))) void*)(gp), \
    (__attribute__((address_space(3))) void*)(lp), 16, 0, 0)

#define MEMFENCE asm volatile("" ::: "memory")

// ---------------------------------------------------------------------------
// fp32 -> bf16 elementwise convert
// ---------------------------------------------------------------------------
__global__ __launch_bounds__(256)
void f32_to_bf16_vec(const float* __restrict__ in, __bf16* __restrict__ out)
{
    const size_t i = ((size_t)blockIdx.x * 256 + threadIdx.x) * 8;
    fx4 a = *(const fx4*)(in + i);
    fx4 b = *(const fx4*)(in + i + 4);
    bx8 u;
    u[0] = (__bf16)a[0]; u[1] = (__bf16)a[1]; u[2] = (__bf16)a[2]; u[3] = (__bf16)a[3];
    u[4] = (__bf16)b[0]; u[5] = (__bf16)b[1]; u[6] = (__bf16)b[2]; u[7] = (__bf16)b[3];
    *(bx8*)(out + i) = u;
}

// ---------------------------------------------------------------------------
// fp32 [R][C] -> bf16 [C][R] transpose (64x64 tiles via LDS).
// SCALE != nullptr: multiply element (r,c) by scale[r] (per input-row scale).
// ---------------------------------------------------------------------------
__global__ __launch_bounds__(256)
void transpose_f32_to_bf16(const float* __restrict__ in, __bf16* __restrict__ out,
                           const float* __restrict__ scale, int R, int C)
{
    __shared__ float t[64][65];
    const int tid = threadIdx.x;
    const int r0 = blockIdx.y * 64;
    const int c0 = blockIdx.x * 64;
    const int lr = tid >> 4;
    const int lc = (tid & 15) * 4;
#pragma unroll
    for (int p = 0; p < 4; ++p) {
        const int rr = p * 16 + lr;
        const fx4 v = *(const fx4*)(in + (size_t)(r0 + rr) * C + c0 + lc);
        t[rr][lc + 0] = v[0]; t[rr][lc + 1] = v[1];
        t[rr][lc + 2] = v[2]; t[rr][lc + 3] = v[3];
    }
    __syncthreads();
    const int oc = tid >> 2;
    const int ob = (tid & 3) * 16;
    bx8 u0, u1;
    if (scale) {
#pragma unroll
        for (int j = 0; j < 8; ++j) {
            u0[j] = (__bf16)(t[ob + j][oc]     * scale[r0 + ob + j]);
            u1[j] = (__bf16)(t[ob + 8 + j][oc] * scale[r0 + ob + 8 + j]);
        }
    } else {
#pragma unroll
        for (int j = 0; j < 8; ++j) {
            u0[j] = (__bf16)t[ob + j][oc];
            u1[j] = (__bf16)t[ob + 8 + j][oc];
        }
    }
    *(bx8*)(out + (size_t)(c0 + oc) * R + r0 + ob)     = u0;
    *(bx8*)(out + (size_t)(c0 + oc) * R + r0 + ob + 8) = u1;
}

// ---------------------------------------------------------------------------
// rowsum_inv: inv[row] = 1 / sum(W[row][:]).  One block per row.
// ---------------------------------------------------------------------------
__global__ __launch_bounds__(256)
void rowsum_inv(const __bf16* __restrict__ W, float* __restrict__ inv)
{
    const __bf16* row = W + (size_t)blockIdx.x * MEMN;
    const int tid = threadIdx.x;
    float s = 0.f;
#pragma unroll
    for (int i = 0; i < 4; ++i) {
        bx8 u = *(const bx8*)(row + i * 2048 + tid * 8);
#pragma unroll
        for (int j = 0; j < 8; ++j) s += (float)u[j];
    }
#pragma unroll
    for (int off = 32; off >= 1; off >>= 1) s += __shfl_xor(s, off, 64);
    __shared__ float red[4];
    const int wave = tid >> 6, lane = tid & 63;
    if (lane == 0) red[wave] = s;
    __syncthreads();
    if (tid == 0)
        inv[blockIdx.x] = 1.0f / ((red[0] + red[1]) + (red[2] + red[3]));
}

// ---------------------------------------------------------------------------
// colsum_partial: part[chunk][s] = sum over 128 rows of W[m][s].
// grid (4, 64): x = 2048-col range, y = 128-row chunk. Coalesced bx8 reads.
// ---------------------------------------------------------------------------
__global__ __launch_bounds__(256)
void colsum_partial(const __bf16* __restrict__ W, float* __restrict__ part)
{
    const int s0 = blockIdx.x * 2048 + threadIdx.x * 8;
    const int m0 = blockIdx.y * 128;
    fx4 a0 = {}, a1 = {};
    for (int r = 0; r < 128; ++r) {
        bx8 u = *(const bx8*)(W + (size_t)(m0 + r) * MEMN + s0);
        a0[0] += (float)u[0]; a0[1] += (float)u[1];
        a0[2] += (float)u[2]; a0[3] += (float)u[3];
        a1[0] += (float)u[4]; a1[1] += (float)u[5];
        a1[2] += (float)u[6]; a1[3] += (float)u[7];
    }
    *(fx4*)(part + (size_t)blockIdx.y * MEMN + s0)     = a0;
    *(fx4*)(part + (size_t)blockIdx.y * MEMN + s0 + 4) = a1;
}

// ---------------------------------------------------------------------------
// colsum_finalize: invc[s] = 1 / sum_c part[c][s].  grid 32 x 256 threads.
// ---------------------------------------------------------------------------
__global__ __launch_bounds__(256)
void colsum_finalize(const float* __restrict__ part, float* __restrict__ invc)
{
    const int s = blockIdx.x * 256 + threadIdx.x;
    float t = 0.f;
#pragma unroll 8
    for (int c = 0; c < 64; ++c) t += part[(size_t)c * MEMN + s];
    invc[s] = 1.0f / t;
}

// ---------------------------------------------------------------------------
// gemm8: round-3 verified NT GEMM core (ring-4 LDS, one counted vmcnt + one
// barrier per K-tile, PMC-verified conflict-free swizzle). Epilogue modes:
//   MODE 2: f32 out = c + add[idx]                  (write PV)
//   MODE 3: bf16 out = exp(c + bias[col])           (read logits, unnormalized)
//   MODE 4: bf16 out = exp(c + bias[row])           (write logits -> W^T)
//   MODE 5: f32 out = c * bias[row]                 (read PV, bias = 1/rowsum)
// ---------------------------------------------------------------------------
template <int BM, int BN, int MODE>
__global__ __launch_bounds__(512)
void gemm8(const __bf16* __restrict__ A, const __bf16* __restrict__ B,
           const float* __restrict__ bias, const float* __restrict__ add,
           void* __restrict__ out, int N, int K, int nBN)
{
    constexpr int ASZ = BM * 64;
    constexpr int BSZ = BN * 64;
    constexpr int RA  = BM / 128;
    constexpr int RB  = BN / 128;
    constexpr int L   = RA + RB;
    constexpr int RWM = BM / 2, RWN = BN / 4;
    constexpr int FM  = RWM / 16, FN = RWN / 16;

    __shared__ __align__(16) char smem[4 * (ASZ + BSZ)];

    const int tid = threadIdx.x;
    const int wid = tid >> 6;
    const int ln  = tid & 63;
    const int fl  = ln & 15;
    const int fh  = ln >> 4;
    const int wr  = wid >> 2;
    const int wc  = wid & 3;

    const int nwg = gridDim.x;
    const int bid = blockIdx.x;
    const int wg  = (bid & 7) * (nwg >> 3) + (bid >> 3);
    const int tm  = (wg / nBN) * BM;
    const int tn  = (wg % nBN) * BN;

    const int NT = K / 32;

    const __bf16* Ag[RA];
    const __bf16* Bg[RB];
#pragma unroll
    for (int R = 0; R < RA; ++R) {
        const int p = R * 512 + tid;
        Ag[R] = A + (size_t)(tm + (p >> 2)) * K + ((p & 3) ^ ((p >> 3) & 3)) * 8;
    }
#pragma unroll
    for (int R = 0; R < RB; ++R) {
        const int p = R * 512 + tid;
        Bg[R] = B + (size_t)(tn + (p >> 2)) * K + ((p & 3) ^ ((p >> 3) & 3)) * 8;
    }

    auto stage = [&](int t) {
        const int s = t & 3;
        const size_t ko = (size_t)t * 32;
        char* Ad = smem + s * ASZ + wid * 1024;
        char* Bd = smem + 4 * ASZ + s * BSZ + wid * 1024;
#pragma unroll
        for (int R = 0; R < RA; ++R) GLDS(Ag[R] + ko, Ad + R * 8192);
#pragma unroll
        for (int R = 0; R < RB; ++R) GLDS(Bg[R] + ko, Bd + R * 8192);
    };

    fx4 acc[FM][FN] = {};

    stage(0);
    if (NT > 1) stage(1);

    for (int t = 0; t < NT; ++t) {
        if (t == NT - 1) {
            asm volatile("s_waitcnt vmcnt(0)" ::: "memory");
        } else {
            asm volatile("s_waitcnt vmcnt(%0)" :: "i"(L) : "memory");
        }
        __builtin_amdgcn_s_barrier();
        MEMFENCE;
        if (t + 2 < NT) stage(t + 2);

        const char* Ab = smem + (t & 3) * ASZ;
        const char* Bb = smem + 4 * ASZ + (t & 3) * BSZ;
        bx8 fa[FM], fb[FN];
#pragma unroll
        for (int mi = 0; mi < FM; ++mi) {
            const int r = wr * RWM + mi * 16 + fl;
            fa[mi] = *(const bx8*)(Ab + r * 64 + ((fh ^ ((r >> 1) & 3)) << 4));
        }
#pragma unroll
        for (int ni = 0; ni < FN; ++ni) {
            const int c = wc * RWN + ni * 16 + fl;
            fb[ni] = *(const bx8*)(Bb + c * 64 + ((fh ^ ((c >> 1) & 3)) << 4));
        }
        __builtin_amdgcn_s_setprio(1);
#pragma unroll
        for (int mi = 0; mi < FM; ++mi)
#pragma unroll
            for (int ni = 0; ni < FN; ++ni)
                acc[mi][ni] = __builtin_amdgcn_mfma_f32_16x16x32_bf16(
                    fa[mi], fb[ni], acc[mi][ni], 0, 0, 0);
        __builtin_amdgcn_s_setprio(0);
    }

    // epilogue: C/D layout col = lane&15, row = (lane>>4)*4 + reg
#pragma unroll
    for (int mi = 0; mi < FM; ++mi) {
#pragma unroll
        for (int ni = 0; ni < FN; ++ni) {
            const int gr0 = tm + wr * RWM + mi * 16 + fh * 4;
            const int gc  = tn + wc * RWN + ni * 16 + fl;
            fx4 c = acc[mi][ni];
            if constexpr (MODE == 2) {
                float* O = (float*)out;
#pragma unroll
                for (int j = 0; j < 4; ++j) {
                    const size_t idx = (size_t)(gr0 + j) * N + gc;
                    O[idx] = c[j] + add[idx];
                }
            } else if constexpr (MODE == 3) {
                __bf16* O = (__bf16*)out;
                const float bv = bias[gc];
#pragma unroll
                for (int j = 0; j < 4; ++j)
                    O[(size_t)(gr0 + j) * N + gc] = (__bf16)__expf(c[j] + bv);
            } else if constexpr (MODE == 4) {
                __bf16* O = (__bf16*)out;
#pragma unroll
                for (int j = 0; j < 4; ++j)
                    O[(size_t)(gr0 + j) * N + gc] =
                        (__bf16)__expf(c[j] + bias[gr0 + j]);
            } else {   // MODE 5
                float* O = (float*)out;
#pragma unroll
                for (int j = 0; j < 4; ++j)
                    O[(size_t)(gr0 + j) * N + gc] = c[j] * bias[gr0 + j];
            }
        }
    }
}

// ---------------------------------------------------------------------------
// Orchestration. ws layout (176 MiB):
//   xb    [8192,1024] bf16  @ 0
//   slot1 @ 16 MiB : rwb (16MB) -> invr (32KB) -> wwb (16MB) -> colsum part
//                    (2MB) + invc (32KB @ +4MiB)
//   slot2 @ 32 MiB : memT, then xT*invc
//   W     @ 48 MiB : exp(read logits), then exp(write logits)^T  (unnormalized)
// Softmax normalization is folded: read PV scales output rows by invr;
// write PV scales the xT operand by invc. No softmax / transpose passes.
// ---------------------------------------------------------------------------
extern "C" void kernel_launch(void* const* d_in, const int* in_sizes, int n_in,
                              void* d_out, int out_size, void* d_ws, size_t ws_size,
                              hipStream_t stream)
{
    const float* x       = (const float*)d_in[0];
    const float* memory  = (const float*)d_in[1];
    const float* read_w  = (const float*)d_in[2];
    const float* read_b  = (const float*)d_in[3];
    const float* write_w = (const float*)d_in[4];
    const float* write_b = (const float*)d_in[5];

    float* out_read = (float*)d_out;
    float* out_mem  = (float*)d_out + (size_t)MEMN * HID;

    char* p = (char*)d_ws;
    const size_t MiB = 1024 * 1024;
    __bf16* xb    = (__bf16*)(p + 0 * MiB);
    __bf16* slot1 = (__bf16*)(p + 16 * MiB);
    __bf16* slot2 = (__bf16*)(p + 32 * MiB);
    __bf16* W     = (__bf16*)(p + 48 * MiB);
    float*  invr  = (float*)(p + 16 * MiB);          // after rwb dead
    float*  part  = (float*)(p + 16 * MiB);          // after wwb dead (2 MB)
    float*  invc  = (float*)(p + 20 * MiB);          // 32 KB

    // ---- read path ---------------------------------------------------------
    f32_to_bf16_vec<<<4096, 256, 0, stream>>>(x, xb);
    f32_to_bf16_vec<<<4096, 256, 0, stream>>>(read_w, slot1);
    transpose_f32_to_bf16<<<dim3(HID / 64, ROWS / 64), 256, 0, stream>>>(
        memory, slot2, nullptr, ROWS, HID);
    // W[s][m] = exp(x.rw^T + rb)   (unnormalized softmax numerators)
    gemm8<256, 256, 3><<<(ROWS / 256) * (MEMN / 256), 512, 0, stream>>>(
        xb, slot1, read_b, nullptr, W, MEMN, HID, MEMN / 256);
    rowsum_inv<<<ROWS, 256, 0, stream>>>(W, invr);
    // out_read[s][h] = invr[s] * sum_m W[s,m] mem[m,h]
    gemm8<128, 256, 5><<<(ROWS / 128) * (HID / 256), 512, 0, stream>>>(
        W, slot2, invr, nullptr, out_read, HID, MEMN, HID / 256);

    // ---- write path --------------------------------------------------------
    f32_to_bf16_vec<<<4096, 256, 0, stream>>>(write_w, slot1);
    // W^T[m][s] = exp(ww.x^T + wb[m])  -- transposed logits, no transpose pass
    gemm8<256, 256, 4><<<(MEMN / 256) * (ROWS / 256), 512, 0, stream>>>(
        slot1, xb, write_b, nullptr, W, ROWS, HID, ROWS / 256);
    colsum_partial<<<dim3(4, 64), 256, 0, stream>>>(W, part);
    colsum_finalize<<<32, 256, 0, stream>>>(part, invc);
    // xT[h][s] = x[s][h] * invc[s]
    transpose_f32_to_bf16<<<dim3(HID / 64, ROWS / 64), 256, 0, stream>>>(
        x, slot2, invc, ROWS, HID);
    // out_mem[m][h] = memory[m,h] + sum_s W^T[m,s] * xT[h,s]
    gemm8<128, 256, 2><<<(MEMN / 128) * (HID / 256), 512, 0, stream>>>(
        W, slot2, nullptr, memory, out_mem, HID, ROWS, HID / 256);
}